// Round 1
// baseline (976.346 us; speedup 1.0000x reference)
//
#include <hip/hip_runtime.h>
#include <math.h>

typedef float2 cplx;

__device__ __forceinline__ cplx cmul(cplx a, cplx b) {
    return make_float2(a.x * b.x - a.y * b.y, a.x * b.y + a.y * b.x);
}
__device__ __forceinline__ cplx conjf2(cplx a) { return make_float2(a.x, -a.y); }
__device__ __forceinline__ int br8(int x) { return (int)(__brev((unsigned)x) >> 24); }
__device__ __forceinline__ int br9(int x) { return (int)(__brev((unsigned)x) >> 23); }

// C buffer: [256 t][256 h][256 w] cplx (134.2 MB).
// Compact "A" array ([256 t][128 h][128 w]) is aliased into rows h in [128,256):
// those rows are dead at the times A is alive (verified read/write chain).
__device__ __forceinline__ size_t idxC(int t, int h, int w) {
    return ((size_t)t * 256 + h) * 256 + w;
}
__device__ __forceinline__ size_t idxA(int t, int h, int w) {
    return ((size_t)t * 256 + 128 + h) * 256 + w;
}

// K1: tmp[m,h,w] = sum_t mtx[m,t] * gridz[t]^4 * feature[d,t,h,w], packed d0+i*d1.
// mtx rows are ~99.6% sparse -> skip zeros (block-uniform branch).
__global__ __launch_bounds__(128) void k1_resample(
        const float* __restrict__ feat, const float* __restrict__ gridz,
        const float* __restrict__ mtx, cplx* __restrict__ C) {
    int m = blockIdx.x, h = blockIdx.y, w = threadIdx.x;
    __shared__ float coeff[256];
    for (int k = threadIdx.x; k < 256; k += 128) {
        float g = gridz[k];
        float g2 = g * g;
        coeff[k] = mtx[m * 256 + k] * (g2 * g2);
    }
    __syncthreads();
    float a0 = 0.f, a1 = 0.f;
    for (int t = 0; t < 256; ++t) {
        float c = coeff[t];
        if (c != 0.0f) {
            size_t o = ((size_t)t * 128 + h) * 128 + w;
            a0 += c * feat[o];
            a1 += c * feat[o + (size_t)256 * 128 * 128];
        }
    }
    C[idxA(m, h, w)] = make_float2(a0, a1);
}

// K2: forward 256-FFT along w for lines (t<256, h<128); input w<128 + zero pad.
__global__ __launch_bounds__(128) void k2_fftw(cplx* __restrict__ C) {
    int t = blockIdx.x, h = blockIdx.y, i = threadIdx.x;
    __shared__ cplx buf[256];
    __shared__ cplx tw[128];
    {
        float s, c, ang = -(float)M_PI * (float)i / 128.0f; // -2*pi*i/256
        sincosf(ang, &s, &c);
        tw[i] = make_float2(c, s);
    }
    buf[br8(i)] = C[idxA(t, h, i)];
    buf[br8(i + 128)] = make_float2(0.f, 0.f);
    __syncthreads();
    for (int s = 1; s <= 8; ++s) {
        int half = 1 << (s - 1);
        int j = i & (half - 1);
        int i0 = ((i >> (s - 1)) << s) + j;
        int i1 = i0 + half;
        cplx w = tw[j << (8 - s)];
        cplx a = buf[i0], b = cmul(w, buf[i1]);
        buf[i0] = make_float2(a.x + b.x, a.y + b.y);
        buf[i1] = make_float2(a.x - b.x, a.y - b.y);
        __syncthreads();
    }
    C[idxC(t, h, i)] = buf[i];
    C[idxC(t, h, i + 128)] = buf[i + 128];
}

// K3: forward 256-FFT along h (reads h<128, pad; writes all h). 16 w-columns/block.
__global__ __launch_bounds__(256) void k3_ffth(cplx* __restrict__ C) {
    int t = blockIdx.x, w0 = blockIdx.y * 16;
    int tid = threadIdx.x, ww = tid & 15, q = tid >> 4; // q in [0,16)
    __shared__ cplx buf[256 * 17]; // pad 16->17 to break bank conflicts
    __shared__ cplx tw[128];
    if (tid < 128) {
        float s, c, ang = -(float)M_PI * (float)tid / 128.0f;
        sincosf(ang, &s, &c);
        tw[tid] = make_float2(c, s);
    }
    for (int h = q; h < 256; h += 16) {
        cplx v = (h < 128) ? C[idxC(t, h, w0 + ww)] : make_float2(0.f, 0.f);
        buf[br8(h) * 17 + ww] = v;
    }
    __syncthreads();
    for (int s = 1; s <= 8; ++s) {
        int half = 1 << (s - 1);
        for (int jj = 0; jj < 8; ++jj) {
            int bf = q + (jj << 4);
            int j = bf & (half - 1);
            int i0 = ((bf >> (s - 1)) << s) + j;
            int i1 = i0 + half;
            cplx w = tw[j << (8 - s)];
            cplx a = buf[i0 * 17 + ww], b = cmul(w, buf[i1 * 17 + ww]);
            buf[i0 * 17 + ww] = make_float2(a.x + b.x, a.y + b.y);
            buf[i1 * 17 + ww] = make_float2(a.x - b.x, a.y - b.y);
        }
        __syncthreads();
    }
    for (int h = q; h < 256; h += 16)
        C[idxC(t, h, w0 + ww)] = buf[h * 17 + ww];
}

// K4: fused T-pass per (h, w-tile): pad->512 fwd FFT -> invpsf multiply (+1/N) ->
// 512 inv FFT -> write t<256. The 512-long axis lives only in LDS.
__global__ __launch_bounds__(256) void k4_fftt(
        cplx* __restrict__ C, const float* __restrict__ pr, const float* __restrict__ pim) {
    int h = blockIdx.x, w0 = blockIdx.y * 8;
    int tid = threadIdx.x, ww = tid & 7, q = tid >> 3; // q in [0,32)
    __shared__ cplx buf[512 * 9]; // pad 8->9
    __shared__ cplx tw[256];
    {
        float s, c, ang = -(float)M_PI * (float)tid / 256.0f; // -2*pi*tid/512
        sincosf(ang, &s, &c);
        tw[tid] = make_float2(c, s);
    }
    for (int t = q; t < 512; t += 32) {
        cplx v = (t < 256) ? C[idxC(t, h, w0 + ww)] : make_float2(0.f, 0.f);
        buf[br9(t) * 9 + ww] = v;
    }
    __syncthreads();
    // forward DIT (bit-reversed in, natural out)
    for (int s = 1; s <= 9; ++s) {
        int half = 1 << (s - 1);
        for (int jj = 0; jj < 8; ++jj) {
            int bf = q + (jj << 5);
            int j = bf & (half - 1);
            int i0 = ((bf >> (s - 1)) << s) + j;
            int i1 = i0 + half;
            cplx w = tw[j << (9 - s)];
            cplx a = buf[i0 * 9 + ww], b = cmul(w, buf[i1 * 9 + ww]);
            buf[i0 * 9 + ww] = make_float2(a.x + b.x, a.y + b.y);
            buf[i1 * 9 + ww] = make_float2(a.x - b.x, a.y - b.y);
        }
        __syncthreads();
    }
    const float S = 1.0f / (512.0f * 256.0f * 256.0f); // full ifftn scale
    for (int t = q; t < 512; t += 32) {
        size_t g = ((size_t)t * 256 + h) * 256 + (w0 + ww);
        cplx p = make_float2(pr[g] * S, pim[g] * S);
        buf[t * 9 + ww] = cmul(buf[t * 9 + ww], p);
    }
    __syncthreads();
    // inverse DIF (natural in, bit-reversed out), conjugate twiddles
    for (int s = 9; s >= 1; --s) {
        int half = 1 << (s - 1);
        for (int jj = 0; jj < 8; ++jj) {
            int bf = q + (jj << 5);
            int j = bf & (half - 1);
            int i0 = ((bf >> (s - 1)) << s) + j;
            int i1 = i0 + half;
            cplx a = buf[i0 * 9 + ww], b = buf[i1 * 9 + ww];
            buf[i0 * 9 + ww] = make_float2(a.x + b.x, a.y + b.y);
            cplx w = conjf2(tw[j << (9 - s)]);
            cplx d = make_float2(a.x - b.x, a.y - b.y);
            buf[i1 * 9 + ww] = cmul(w, d);
        }
        __syncthreads();
    }
    for (int t = q; t < 256; t += 32)
        C[idxC(t, h, w0 + ww)] = buf[br9(t) * 9 + ww];
}

// K5: inverse 256-FFT along h; write only h<128 (crop).
__global__ __launch_bounds__(256) void k5_iffth(cplx* __restrict__ C) {
    int t = blockIdx.x, w0 = blockIdx.y * 16;
    int tid = threadIdx.x, ww = tid & 15, q = tid >> 4;
    __shared__ cplx buf[256 * 17];
    __shared__ cplx tw[128];
    if (tid < 128) {
        float s, c, ang = -(float)M_PI * (float)tid / 128.0f;
        sincosf(ang, &s, &c);
        tw[tid] = make_float2(c, s);
    }
    for (int h = q; h < 256; h += 16)
        buf[h * 17 + ww] = C[idxC(t, h, w0 + ww)];
    __syncthreads();
    for (int s = 8; s >= 1; --s) {
        int half = 1 << (s - 1);
        for (int jj = 0; jj < 8; ++jj) {
            int bf = q + (jj << 4);
            int j = bf & (half - 1);
            int i0 = ((bf >> (s - 1)) << s) + j;
            int i1 = i0 + half;
            cplx a = buf[i0 * 17 + ww], b = buf[i1 * 17 + ww];
            buf[i0 * 17 + ww] = make_float2(a.x + b.x, a.y + b.y);
            cplx w = conjf2(tw[j << (8 - s)]);
            cplx d = make_float2(a.x - b.x, a.y - b.y);
            buf[i1 * 17 + ww] = cmul(w, d);
        }
        __syncthreads();
    }
    for (int h = q; h < 128; h += 16)
        C[idxC(t, h, w0 + ww)] = buf[br8(h) * 17 + ww];
}

// K6: inverse 256-FFT along w; write w<128 (crop) into aliased A region.
__global__ __launch_bounds__(128) void k6_ifftw(cplx* __restrict__ C) {
    int t = blockIdx.x, h = blockIdx.y, i = threadIdx.x;
    __shared__ cplx buf[256];
    __shared__ cplx tw[128];
    {
        float s, c, ang = -(float)M_PI * (float)i / 128.0f;
        sincosf(ang, &s, &c);
        tw[i] = make_float2(c, s);
    }
    buf[i] = C[idxC(t, h, i)];
    buf[i + 128] = C[idxC(t, h, i + 128)];
    __syncthreads();
    for (int s = 8; s >= 1; --s) {
        int half = 1 << (s - 1);
        int j = i & (half - 1);
        int i0 = ((i >> (s - 1)) << s) + j;
        int i1 = i0 + half;
        cplx a = buf[i0], b = buf[i1];
        buf[i0] = make_float2(a.x + b.x, a.y + b.y);
        cplx w = conjf2(tw[j << (8 - s)]);
        cplx d = make_float2(a.x - b.x, a.y - b.y);
        buf[i1] = cmul(w, d);
        __syncthreads();
    }
    C[idxA(t, h, i)] = buf[br8(i)];
}

// K7: out[d,m,h,w] = sum_t mtxi[m,t] * vol[t,h,w]; Re->d0, Im->d1. Skip zero rows.
__global__ __launch_bounds__(128) void k7_out(
        const cplx* __restrict__ C, const float* __restrict__ mtxi,
        float* __restrict__ out) {
    int m = blockIdx.x, h = blockIdx.y, w = threadIdx.x;
    __shared__ float coeff[256];
    for (int k = threadIdx.x; k < 256; k += 128)
        coeff[k] = mtxi[m * 256 + k];
    __syncthreads();
    float a0 = 0.f, a1 = 0.f;
    for (int t = 0; t < 256; ++t) {
        float c = coeff[t];
        if (c != 0.0f) {
            cplx v = C[idxA(t, h, w)];
            a0 += c * v.x;
            a1 += c * v.y;
        }
    }
    out[((size_t)m * 128 + h) * 128 + w] = a0;
    out[(((size_t)256 + m) * 128 + h) * 128 + w] = a1;
}

extern "C" void kernel_launch(void* const* d_in, const int* in_sizes, int n_in,
                              void* d_out, int out_size, void* d_ws, size_t ws_size,
                              hipStream_t stream) {
    const float* feat  = (const float*)d_in[0];
    const float* gridz = (const float*)d_in[1];
    const float* mtx   = (const float*)d_in[2];
    const float* mtxi  = (const float*)d_in[3];
    const float* pr    = (const float*)d_in[4];
    const float* pim   = (const float*)d_in[5];
    cplx* C = (cplx*)d_ws; // needs 256*256*256*8 = 134,217,728 bytes
    float* out = (float*)d_out;

    k1_resample<<<dim3(256, 128), 128, 0, stream>>>(feat, gridz, mtx, C);
    k2_fftw    <<<dim3(256, 128), 128, 0, stream>>>(C);
    k3_ffth    <<<dim3(256, 16), 256, 0, stream>>>(C);
    k4_fftt    <<<dim3(256, 32), 256, 0, stream>>>(C, pr, pim);
    k5_iffth   <<<dim3(256, 16), 256, 0, stream>>>(C);
    k6_ifftw   <<<dim3(256, 128), 128, 0, stream>>>(C);
    k7_out     <<<dim3(256, 128), 128, 0, stream>>>(C, mtxi, out);
}

// Round 2
// 803.188 us; speedup vs baseline: 1.2156x; 1.2156x over previous
//
#include <hip/hip_runtime.h>
#include <math.h>

typedef float2 cplx;
#define PI_F 3.14159265358979323846f
#define C8F 0.70710678118654752440f

__device__ __forceinline__ cplx cadd(cplx a, cplx b){ return make_float2(a.x+b.x, a.y+b.y); }
__device__ __forceinline__ cplx csub(cplx a, cplx b){ return make_float2(a.x-b.x, a.y-b.y); }
__device__ __forceinline__ cplx cmul(cplx a, cplx b){ return make_float2(a.x*b.x - a.y*b.y, a.x*b.y + a.y*b.x); }
// a * conj(b)
__device__ __forceinline__ cplx cmulc(cplx a, cplx b){ return make_float2(a.x*b.x + a.y*b.y, a.y*b.x - a.x*b.y); }

// 8-point DFT, natural order in/out. INV=false: W8^{-nk}; INV=true: W8^{+nk}.
template<bool INV>
__device__ __forceinline__ void dft8(cplx* v) {
    cplx t0 = cadd(v[0], v[4]), u0 = csub(v[0], v[4]);
    cplx t1 = cadd(v[1], v[5]), u1 = csub(v[1], v[5]);
    cplx t2 = cadd(v[2], v[6]), u2 = csub(v[2], v[6]);
    cplx t3 = cadd(v[3], v[7]), u3 = csub(v[3], v[7]);
    if (!INV) {
        u1 = make_float2(C8F*(u1.x + u1.y), C8F*(u1.y - u1.x));   // *W8^1
        u2 = make_float2(u2.y, -u2.x);                            // *-i
        u3 = make_float2(C8F*(u3.y - u3.x), -C8F*(u3.x + u3.y));  // *W8^3
    } else {
        u1 = make_float2(C8F*(u1.x - u1.y), C8F*(u1.x + u1.y));
        u2 = make_float2(-u2.y, u2.x);
        u3 = make_float2(-C8F*(u3.x + u3.y), C8F*(u3.x - u3.y));
    }
    cplx b0 = cadd(t0,t2), b1 = cadd(t1,t3), b2 = csub(t0,t2), b3 = csub(t1,t3);
    b3 = INV ? make_float2(-b3.y, b3.x) : make_float2(b3.y, -b3.x);
    v[0] = cadd(b0,b1); v[4] = csub(b0,b1); v[2] = cadd(b2,b3); v[6] = csub(b2,b3);
    cplx c0 = cadd(u0,u2), c1 = cadd(u1,u3), c2 = csub(u0,u2), c3 = csub(u1,u3);
    c3 = INV ? make_float2(-c3.y, c3.x) : make_float2(c3.y, -c3.x);
    v[1] = cadd(c0,c1); v[5] = csub(c0,c1); v[3] = cadd(c2,c3); v[7] = csub(c2,c3);
}

template<bool INV>
__device__ __forceinline__ void dft4(cplx* v) {
    cplx b0 = cadd(v[0], v[2]), b2 = csub(v[0], v[2]);
    cplx b1 = cadd(v[1], v[3]), b3 = csub(v[1], v[3]);
    b3 = INV ? make_float2(-b3.y, b3.x) : make_float2(b3.y, -b3.x);
    v[0] = cadd(b0,b1); v[2] = csub(b0,b1); v[1] = cadd(b2,b3); v[3] = csub(b2,b3);
}

// C buffer: [256 t][256 h][256 w] cplx (134.2 MB).
// Compact "A" array ([256 t][128 h][128 w]) aliased into rows h in [128,256).
__device__ __forceinline__ size_t idxC(int t, int h, int w) {
    return ((size_t)t * 256 + h) * 256 + w;
}
__device__ __forceinline__ size_t idxA(int t, int h, int w) {
    return ((size_t)t * 256 + 128 + h) * 256 + w;
}

// K1: tmp[m,h,w] = sum_t mtx[m,t] * gridz[t]^4 * feature[d,t,h,w], packed d0+i*d1.
__global__ __launch_bounds__(128) void k1_resample(
        const float* __restrict__ feat, const float* __restrict__ gridz,
        const float* __restrict__ mtx, cplx* __restrict__ C) {
    int m = blockIdx.x, h = blockIdx.y, w = threadIdx.x;
    __shared__ float coeff[256];
    for (int k = threadIdx.x; k < 256; k += 128) {
        float g = gridz[k];
        float g2 = g * g;
        coeff[k] = mtx[m * 256 + k] * (g2 * g2);
    }
    __syncthreads();
    float a0 = 0.f, a1 = 0.f;
    for (int t = 0; t < 256; ++t) {
        float c = coeff[t];
        if (c != 0.0f) {
            size_t o = ((size_t)t * 128 + h) * 128 + w;
            a0 += c * feat[o];
            a1 += c * feat[o + (size_t)256 * 128 * 128];
        }
    }
    C[idxA(m, h, w)] = make_float2(a0, a1);
}

// K2: forward 256-FFT along w (8 h-lines/block), input w<128 from A, output all w.
__global__ __launch_bounds__(256, 4) void k2_fftw(cplx* __restrict__ C) {
    const int t = blockIdx.x, h0 = blockIdx.y * 8;
    const int tid = threadIdx.x, ww = tid & 7, q = tid >> 3;
    __shared__ cplx buf[256 * 9];
    __shared__ cplx tw[256];
    {
        float s, c; sincosf(-(2.0f * PI_F / 256.0f) * (float)tid, &s, &c);
        tw[tid] = make_float2(c, s);
    }
    for (int idx = tid; idx < 1024; idx += 256) {       // coalesced stage-in
        int hl = idx >> 7, w = idx & 127;
        buf[w * 9 + hl] = C[idxA(t, h0 + hl, w)];
    }
    __syncthreads();
    {   // stage A (radix-8, stride 32), in-place per-thread octet-set
        cplx x[8];
        #pragma unroll
        for (int p = 0; p < 8; ++p)
            x[p] = (p < 4) ? buf[(q + 32*p) * 9 + ww] : make_float2(0.f, 0.f);
        dft8<false>(x);
        #pragma unroll
        for (int r = 1; r < 8; ++r) x[r] = cmul(x[r], tw[q * r]);
        #pragma unroll
        for (int r = 0; r < 8; ++r) buf[(32*r + q) * 9 + ww] = x[r];
    }
    __syncthreads();
    {   // stage B (radix-8, stride 4 within 32-blocks)
        int r1 = q >> 2, j = q & 3, base = 32*r1 + j;
        cplx y[8];
        #pragma unroll
        for (int p = 0; p < 8; ++p) y[p] = buf[(base + 4*p) * 9 + ww];
        dft8<false>(y);
        #pragma unroll
        for (int r2 = 1; r2 < 8; ++r2) y[r2] = cmul(y[r2], tw[8 * j * r2]);
        #pragma unroll
        for (int r2 = 0; r2 < 8; ++r2) buf[(32*r1 + 4*r2 + j) * 9 + ww] = y[r2];
    }
    __syncthreads();
    cplx z2[2][4]; int kb2[2];
    for (int hi = 0; hi < 2; ++hi) {   // stage C (radix-4) into regs
        int m = q + 32*hi;
        #pragma unroll
        for (int jj = 0; jj < 4; ++jj) z2[hi][jj] = buf[(4*m + jj) * 9 + ww];
        dft4<false>(z2[hi]);
        kb2[hi] = (m >> 3) + 8 * (m & 7);
    }
    __syncthreads();                   // all group-reads done before k-writes
    for (int hi = 0; hi < 2; ++hi) {
        #pragma unroll
        for (int s2 = 0; s2 < 4; ++s2) buf[(kb2[hi] + 64*s2) * 9 + ww] = z2[hi][s2];
    }
    __syncthreads();
    for (int idx = tid; idx < 2048; idx += 256) {       // coalesced stage-out
        int hl = idx >> 8, w = idx & 255;
        C[idxC(t, h0 + hl, w)] = buf[w * 9 + hl];
    }
}

// K3: forward 256-FFT along h (8 w-cols/block), reads h<128, writes all h.
__global__ __launch_bounds__(256, 4) void k3_ffth(cplx* __restrict__ C) {
    const int t = blockIdx.x, w0 = blockIdx.y * 8;
    const int tid = threadIdx.x, ww = tid & 7, q = tid >> 3;
    __shared__ cplx buf[256 * 9];
    __shared__ cplx tw[256];
    {
        float s, c; sincosf(-(2.0f * PI_F / 256.0f) * (float)tid, &s, &c);
        tw[tid] = make_float2(c, s);
    }
    cplx x[8];
    #pragma unroll
    for (int p = 0; p < 8; ++p)
        x[p] = (p < 4) ? C[idxC(t, q + 32*p, w0 + ww)] : make_float2(0.f, 0.f);
    dft8<false>(x);
    __syncthreads();   // tw ready
    #pragma unroll
    for (int r = 1; r < 8; ++r) x[r] = cmul(x[r], tw[q * r]);
    #pragma unroll
    for (int r = 0; r < 8; ++r) buf[(32*r + q) * 9 + ww] = x[r];
    __syncthreads();
    {
        int r1 = q >> 2, j = q & 3, base = 32*r1 + j;
        cplx y[8];
        #pragma unroll
        for (int p = 0; p < 8; ++p) y[p] = buf[(base + 4*p) * 9 + ww];
        dft8<false>(y);
        #pragma unroll
        for (int r2 = 1; r2 < 8; ++r2) y[r2] = cmul(y[r2], tw[8 * j * r2]);
        #pragma unroll
        for (int r2 = 0; r2 < 8; ++r2) buf[(32*r1 + 4*r2 + j) * 9 + ww] = y[r2];
    }
    __syncthreads();
    for (int hi = 0; hi < 2; ++hi) {
        int m = q + 32*hi;
        cplx z[4];
        #pragma unroll
        for (int jj = 0; jj < 4; ++jj) z[jj] = buf[(4*m + jj) * 9 + ww];
        dft4<false>(z);
        int kb = (m >> 3) + 8 * (m & 7);
        #pragma unroll
        for (int s2 = 0; s2 < 4; ++s2)
            C[idxC(t, kb + 64*s2, w0 + ww)] = z[s2];
    }
}

// K4: fused T-pass: pad -> 512 fwd FFT -> invpsf multiply (+scale) -> 512 inv FFT
// -> write t<256. Radix-8^3, 16 cplx/thread, 4 LDS exchanges, 5 syncs.
__global__ __launch_bounds__(256, 4) void k4_fftt(
        cplx* __restrict__ C, const float* __restrict__ pr, const float* __restrict__ pim) {
    const int h = blockIdx.x, w0 = blockIdx.y * 8;
    const int tid = threadIdx.x, ww = tid & 7, q = tid >> 3;
    __shared__ cplx buf[512 * 9];
    __shared__ cplx tw[512];
    for (int e = tid; e < 512; e += 256) {
        float s, c; sincosf(-(2.0f * PI_F / 512.0f) * (float)e, &s, &c);
        tw[e] = make_float2(c, s);
    }
    // stage A (radix-8, stride 64): i = q, q+32
    cplx xa[2][8];
    for (int hi = 0; hi < 2; ++hi) {
        int i = q + 32 * hi;
        #pragma unroll
        for (int p = 0; p < 8; ++p)
            xa[hi][p] = (p < 4) ? C[idxC(i + 64*p, h, w0 + ww)] : make_float2(0.f, 0.f);
        dft8<false>(xa[hi]);
    }
    __syncthreads();   // tw ready
    for (int hi = 0; hi < 2; ++hi) {
        int i = q + 32 * hi;
        #pragma unroll
        for (int r = 1; r < 8; ++r) xa[hi][r] = cmul(xa[hi][r], tw[i * r]);
        #pragma unroll
        for (int r = 0; r < 8; ++r) buf[(64*r + i) * 9 + ww] = xa[hi][r];
    }
    __syncthreads();
    // stage B (radix-8, stride 8 within 64-blocks), in-place per-thread set
    for (int hi = 0; hi < 2; ++hi) {
        int u = q + 32*hi, r1 = u >> 3, j = u & 7, base = 64*r1 + j;
        cplx y[8];
        #pragma unroll
        for (int p = 0; p < 8; ++p) y[p] = buf[(base + 8*p) * 9 + ww];
        dft8<false>(y);
        #pragma unroll
        for (int r2 = 1; r2 < 8; ++r2) y[r2] = cmul(y[r2], tw[8 * j * r2]);
        #pragma unroll
        for (int r2 = 0; r2 < 8; ++r2) buf[(64*r1 + 8*r2 + j) * 9 + ww] = y[r2];
    }
    __syncthreads();
    // stage C (radix-8 over j) + filter + inverse stage C, all in registers
    const float S = 1.0f / (512.0f * 256.0f * 256.0f);
    for (int hi = 0; hi < 2; ++hi) {
        int m = q + 32*hi;
        cplx z[8];
        #pragma unroll
        for (int r = 0; r < 8; ++r) z[r] = buf[(8*m + r) * 9 + ww];
        dft8<false>(z);
        int kb = (m >> 3) + 8 * (m & 7);   // k = kb + 64*s2
        #pragma unroll
        for (int s2 = 0; s2 < 8; ++s2) {
            size_t g = (size_t)(kb + 64*s2) * 65536 + (size_t)h * 256 + (w0 + ww);
            z[s2] = cmul(z[s2], make_float2(pr[g] * S, pim[g] * S));
        }
        dft8<true>(z);
        #pragma unroll
        for (int jj = 0; jj < 8; ++jj) buf[(8*m + jj) * 9 + ww] = z[jj];
    }
    __syncthreads();
    // inverse stage B (conj twiddle before inverse DFT), in-place per-thread set
    for (int hi = 0; hi < 2; ++hi) {
        int u = q + 32*hi, r1 = u >> 3, j = u & 7;
        cplx y[8];
        #pragma unroll
        for (int r2 = 0; r2 < 8; ++r2) y[r2] = buf[(64*r1 + 8*r2 + j) * 9 + ww];
        #pragma unroll
        for (int r2 = 1; r2 < 8; ++r2) y[r2] = cmulc(y[r2], tw[8 * j * r2]);
        dft8<true>(y);
        #pragma unroll
        for (int p = 0; p < 8; ++p) buf[(64*r1 + j + 8*p) * 9 + ww] = y[p];
    }
    __syncthreads();
    // inverse stage A, write t<256
    for (int hi = 0; hi < 2; ++hi) {
        int i = q + 32*hi;
        cplx x[8];
        #pragma unroll
        for (int r = 0; r < 8; ++r) x[r] = buf[(64*r + i) * 9 + ww];
        #pragma unroll
        for (int r = 1; r < 8; ++r) x[r] = cmulc(x[r], tw[i * r]);
        dft8<true>(x);
        #pragma unroll
        for (int p = 0; p < 4; ++p) C[idxC(i + 64*p, h, w0 + ww)] = x[p];
    }
}

// K5: inverse 256-FFT along h, reads all h (freq order), writes h<128 only.
__global__ __launch_bounds__(256, 4) void k5_iffth(cplx* __restrict__ C) {
    const int t = blockIdx.x, w0 = blockIdx.y * 8;
    const int tid = threadIdx.x, ww = tid & 7, q = tid >> 3;
    __shared__ cplx buf[256 * 9];
    __shared__ cplx tw[256];
    {
        float s, c; sincosf(-(2.0f * PI_F / 256.0f) * (float)tid, &s, &c);
        tw[tid] = make_float2(c, s);
    }
    for (int hi = 0; hi < 2; ++hi) {   // inverse stage C: load freq-mapped, inv4
        int m = q + 32*hi, kb = (m >> 3) + 8 * (m & 7);
        cplx z[4];
        #pragma unroll
        for (int s2 = 0; s2 < 4; ++s2) z[s2] = C[idxC(t, kb + 64*s2, w0 + ww)];
        dft4<true>(z);
        #pragma unroll
        for (int jj = 0; jj < 4; ++jj) buf[(4*m + jj) * 9 + ww] = z[jj];
    }
    __syncthreads();   // also covers tw build
    {
        int r1 = q >> 2, j = q & 3;
        cplx y[8];
        #pragma unroll
        for (int r2 = 0; r2 < 8; ++r2) y[r2] = buf[(32*r1 + 4*r2 + j) * 9 + ww];
        #pragma unroll
        for (int r2 = 1; r2 < 8; ++r2) y[r2] = cmulc(y[r2], tw[8 * j * r2]);
        dft8<true>(y);
        #pragma unroll
        for (int p = 0; p < 8; ++p) buf[(32*r1 + j + 4*p) * 9 + ww] = y[p];
    }
    __syncthreads();
    {
        cplx x[8];
        #pragma unroll
        for (int r = 0; r < 8; ++r) x[r] = buf[(32*r + q) * 9 + ww];
        #pragma unroll
        for (int r = 1; r < 8; ++r) x[r] = cmulc(x[r], tw[q * r]);
        dft8<true>(x);
        #pragma unroll
        for (int p = 0; p < 4; ++p) C[idxC(t, q + 32*p, w0 + ww)] = x[p];
    }
}

// K6: inverse 256-FFT along w, writes w<128 into aliased A region.
__global__ __launch_bounds__(256, 4) void k6_ifftw(cplx* __restrict__ C) {
    const int t = blockIdx.x, h0 = blockIdx.y * 8;
    const int tid = threadIdx.x, ww = tid & 7, q = tid >> 3;
    __shared__ cplx buf[256 * 9];
    __shared__ cplx tw[256];
    {
        float s, c; sincosf(-(2.0f * PI_F / 256.0f) * (float)tid, &s, &c);
        tw[tid] = make_float2(c, s);
    }
    for (int idx = tid; idx < 2048; idx += 256) {
        int hl = idx >> 8, w = idx & 255;
        buf[w * 9 + hl] = C[idxC(t, h0 + hl, w)];
    }
    __syncthreads();
    cplx z2[2][4];
    for (int hi = 0; hi < 2; ++hi) {   // inverse stage C from freq-mapped slots
        int m = q + 32*hi, kb = (m >> 3) + 8 * (m & 7);
        #pragma unroll
        for (int s2 = 0; s2 < 4; ++s2) z2[hi][s2] = buf[(kb + 64*s2) * 9 + ww];
        dft4<true>(z2[hi]);
    }
    __syncthreads();   // all freq-reads done before group writes
    for (int hi = 0; hi < 2; ++hi) {
        int m = q + 32*hi;
        #pragma unroll
        for (int jj = 0; jj < 4; ++jj) buf[(4*m + jj) * 9 + ww] = z2[hi][jj];
    }
    __syncthreads();
    {
        int r1 = q >> 2, j = q & 3;
        cplx y[8];
        #pragma unroll
        for (int r2 = 0; r2 < 8; ++r2) y[r2] = buf[(32*r1 + 4*r2 + j) * 9 + ww];
        #pragma unroll
        for (int r2 = 1; r2 < 8; ++r2) y[r2] = cmulc(y[r2], tw[8 * j * r2]);
        dft8<true>(y);
        #pragma unroll
        for (int p = 0; p < 8; ++p) buf[(32*r1 + j + 4*p) * 9 + ww] = y[p];
    }
    __syncthreads();
    {
        cplx x[8];
        #pragma unroll
        for (int r = 0; r < 8; ++r) x[r] = buf[(32*r + q) * 9 + ww];
        #pragma unroll
        for (int r = 1; r < 8; ++r) x[r] = cmulc(x[r], tw[q * r]);
        dft8<true>(x);
        #pragma unroll
        for (int p = 0; p < 4; ++p) buf[(q + 32*p) * 9 + ww] = x[p];   // in-place, w<128
    }
    __syncthreads();
    for (int idx = tid; idx < 1024; idx += 256) {
        int hl = idx >> 7, w = idx & 127;
        C[idxA(t, h0 + hl, w)] = buf[w * 9 + hl];
    }
}

// K7: out[d,m,h,w] = sum_t mtxi[m,t] * vol[t,h,w]; Re->d0, Im->d1.
__global__ __launch_bounds__(128) void k7_out(
        const cplx* __restrict__ C, const float* __restrict__ mtxi,
        float* __restrict__ out) {
    int m = blockIdx.x, h = blockIdx.y, w = threadIdx.x;
    __shared__ float coeff[256];
    for (int k = threadIdx.x; k < 256; k += 128)
        coeff[k] = mtxi[m * 256 + k];
    __syncthreads();
    float a0 = 0.f, a1 = 0.f;
    for (int t = 0; t < 256; ++t) {
        float c = coeff[t];
        if (c != 0.0f) {
            cplx v = C[idxA(t, h, w)];
            a0 += c * v.x;
            a1 += c * v.y;
        }
    }
    out[((size_t)m * 128 + h) * 128 + w] = a0;
    out[(((size_t)256 + m) * 128 + h) * 128 + w] = a1;
}

extern "C" void kernel_launch(void* const* d_in, const int* in_sizes, int n_in,
                              void* d_out, int out_size, void* d_ws, size_t ws_size,
                              hipStream_t stream) {
    const float* feat  = (const float*)d_in[0];
    const float* gridz = (const float*)d_in[1];
    const float* mtx   = (const float*)d_in[2];
    const float* mtxi  = (const float*)d_in[3];
    const float* pr    = (const float*)d_in[4];
    const float* pim   = (const float*)d_in[5];
    cplx* C = (cplx*)d_ws; // 256*256*256*8 = 134,217,728 bytes
    float* out = (float*)d_out;

    k1_resample<<<dim3(256, 128), 128, 0, stream>>>(feat, gridz, mtx, C);
    k2_fftw    <<<dim3(256, 16), 256, 0, stream>>>(C);
    k3_ffth    <<<dim3(256, 32), 256, 0, stream>>>(C);
    k4_fftt    <<<dim3(256, 32), 256, 0, stream>>>(C, pr, pim);
    k5_iffth   <<<dim3(256, 32), 256, 0, stream>>>(C);
    k6_ifftw   <<<dim3(256, 16), 256, 0, stream>>>(C);
    k7_out     <<<dim3(256, 128), 128, 0, stream>>>(C, mtxi, out);
}

// Round 3
// 705.755 us; speedup vs baseline: 1.3834x; 1.1381x over previous
//
#include <hip/hip_runtime.h>
#include <math.h>

typedef float2 cplx;
#define PI_F 3.14159265358979323846f
#define C8F 0.70710678118654752440f

__device__ __forceinline__ cplx cadd(cplx a, cplx b){ return make_float2(a.x+b.x, a.y+b.y); }
__device__ __forceinline__ cplx csub(cplx a, cplx b){ return make_float2(a.x-b.x, a.y-b.y); }
__device__ __forceinline__ cplx cmul(cplx a, cplx b){ return make_float2(a.x*b.x - a.y*b.y, a.x*b.y + a.y*b.x); }
__device__ __forceinline__ cplx cmulc(cplx a, cplx b){ return make_float2(a.x*b.x + a.y*b.y, a.y*b.x - a.x*b.y); }

template<bool INV>
__device__ __forceinline__ void dft8(cplx* v) {
    cplx t0 = cadd(v[0], v[4]), u0 = csub(v[0], v[4]);
    cplx t1 = cadd(v[1], v[5]), u1 = csub(v[1], v[5]);
    cplx t2 = cadd(v[2], v[6]), u2 = csub(v[2], v[6]);
    cplx t3 = cadd(v[3], v[7]), u3 = csub(v[3], v[7]);
    if (!INV) {
        u1 = make_float2(C8F*(u1.x + u1.y), C8F*(u1.y - u1.x));
        u2 = make_float2(u2.y, -u2.x);
        u3 = make_float2(C8F*(u3.y - u3.x), -C8F*(u3.x + u3.y));
    } else {
        u1 = make_float2(C8F*(u1.x - u1.y), C8F*(u1.x + u1.y));
        u2 = make_float2(-u2.y, u2.x);
        u3 = make_float2(-C8F*(u3.x + u3.y), C8F*(u3.x - u3.y));
    }
    cplx b0 = cadd(t0,t2), b1 = cadd(t1,t3), b2 = csub(t0,t2), b3 = csub(t1,t3);
    b3 = INV ? make_float2(-b3.y, b3.x) : make_float2(b3.y, -b3.x);
    v[0] = cadd(b0,b1); v[4] = csub(b0,b1); v[2] = cadd(b2,b3); v[6] = csub(b2,b3);
    cplx c0 = cadd(u0,u2), c1 = cadd(u1,u3), c2 = csub(u0,u2), c3 = csub(u1,u3);
    c3 = INV ? make_float2(-c3.y, c3.x) : make_float2(c3.y, -c3.x);
    v[1] = cadd(c0,c1); v[5] = csub(c0,c1); v[3] = cadd(c2,c3); v[7] = csub(c2,c3);
}

template<bool INV>
__device__ __forceinline__ void dft4(cplx* v) {
    cplx b0 = cadd(v[0], v[2]), b2 = csub(v[0], v[2]);
    cplx b1 = cadd(v[1], v[3]), b3 = csub(v[1], v[3]);
    b3 = INV ? make_float2(-b3.y, b3.x) : make_float2(b3.y, -b3.x);
    v[0] = cadd(b0,b1); v[2] = csub(b0,b1); v[1] = cadd(b2,b3); v[3] = csub(b2,b3);
}

// B: [512 t][256 h][128 w] cplx = 134.2 MB.
// Compact "A" ([256 t][128 h][128 w]) aliased into rows h in [128,256) of t<256.
__device__ __forceinline__ size_t idxB(int t, int h, int w) {
    return ((size_t)t * 256 + h) * 128 + w;
}
__device__ __forceinline__ size_t idxA(int t, int h, int w) {
    return ((size_t)t * 256 + 128 + h) * 128 + w;
}

// K1: A[m,h,w] = sum_t mtx[m,t]*gridz^4*feat, packed d0 + i*d1.
__global__ __launch_bounds__(128) void k1_resample(
        const float* __restrict__ feat, const float* __restrict__ gridz,
        const float* __restrict__ mtx, cplx* __restrict__ B) {
    int m = blockIdx.x, h = blockIdx.y, w = threadIdx.x;
    __shared__ float coeff[256];
    for (int k = threadIdx.x; k < 256; k += 128) {
        float g = gridz[k]; float g2 = g * g;
        coeff[k] = mtx[m * 256 + k] * (g2 * g2);
    }
    __syncthreads();
    float a0 = 0.f, a1 = 0.f;
    for (int t = 0; t < 256; ++t) {
        float c = coeff[t];
        if (c != 0.0f) {
            size_t o = ((size_t)t * 128 + h) * 128 + w;
            a0 += c * feat[o];
            a1 += c * feat[o + (size_t)256 * 128 * 128];
        }
    }
    B[idxA(m, h, w)] = make_float2(a0, a1);
}

// K2: forward 512-FFT along t; reads A (t<256), writes B rows h<128 at all t.
__global__ __launch_bounds__(512, 4) void k2_fftt(cplx* __restrict__ B) {
    const int h = blockIdx.x, w0 = blockIdx.y * 16;
    const int tid = threadIdx.x, ww = tid & 15, q = tid >> 4; // q in [0,32)
    __shared__ cplx buf[512 * 17];
    __shared__ cplx tw[512];
    { float s, c; sincosf(-(2.0f*PI_F/512.0f)*(float)tid, &s, &c); tw[tid] = make_float2(c, s); }
    cplx xa[2][8];
    for (int hi = 0; hi < 2; ++hi) {
        int u = q + 32*hi;
        #pragma unroll
        for (int p = 0; p < 8; ++p)
            xa[hi][p] = (p < 4) ? B[idxA(u + 64*p, h, w0 + ww)] : make_float2(0.f, 0.f);
    }
    dft8<false>(xa[0]); dft8<false>(xa[1]);
    __syncthreads();   // tw ready
    for (int hi = 0; hi < 2; ++hi) {
        int u = q + 32*hi;
        #pragma unroll
        for (int r = 1; r < 8; ++r) xa[hi][r] = cmul(xa[hi][r], tw[u * r]);
        #pragma unroll
        for (int r = 0; r < 8; ++r) buf[(64*r + u) * 17 + ww] = xa[hi][r];
    }
    __syncthreads();
    for (int hi = 0; hi < 2; ++hi) {
        int u = q + 32*hi, r1 = u >> 3, j = u & 7, base = 64*r1 + j;
        cplx y[8];
        #pragma unroll
        for (int p = 0; p < 8; ++p) y[p] = buf[(base + 8*p) * 17 + ww];
        dft8<false>(y);
        #pragma unroll
        for (int r2 = 1; r2 < 8; ++r2) y[r2] = cmul(y[r2], tw[8 * j * r2]);
        #pragma unroll
        for (int r2 = 0; r2 < 8; ++r2) buf[(base + 8*r2) * 17 + ww] = y[r2];
    }
    __syncthreads();
    for (int hi = 0; hi < 2; ++hi) {
        int m = q + 32*hi;
        cplx z[8];
        #pragma unroll
        for (int r = 0; r < 8; ++r) z[r] = buf[(8*m + r) * 17 + ww];
        dft8<false>(z);
        int kb = (m >> 3) + 8 * (m & 7);
        #pragma unroll
        for (int s2 = 0; s2 < 8; ++s2)
            B[idxB(kb + 64*s2, h, w0 + ww)] = z[s2];
    }
}

// K3: forward 256-FFT along h; reads h<128, writes all h (per (t, w-tile) in place).
__global__ __launch_bounds__(256, 4) void k3_ffth(cplx* __restrict__ B) {
    const int t = blockIdx.x, w0 = blockIdx.y * 16;
    const int tid = threadIdx.x, ww = tid & 15, q = tid >> 4; // q in [0,16)
    __shared__ cplx buf[256 * 17];
    __shared__ cplx tw[256];
    { float s, c; sincosf(-(2.0f*PI_F/256.0f)*(float)tid, &s, &c); tw[tid] = make_float2(c, s); }
    cplx xa[2][8];
    for (int hi = 0; hi < 2; ++hi) {
        int u = q + 16*hi;
        #pragma unroll
        for (int p = 0; p < 8; ++p)
            xa[hi][p] = (p < 4) ? B[idxB(t, u + 32*p, w0 + ww)] : make_float2(0.f, 0.f);
    }
    dft8<false>(xa[0]); dft8<false>(xa[1]);
    __syncthreads();
    for (int hi = 0; hi < 2; ++hi) {
        int u = q + 16*hi;
        #pragma unroll
        for (int r = 1; r < 8; ++r) xa[hi][r] = cmul(xa[hi][r], tw[u * r]);
        #pragma unroll
        for (int r = 0; r < 8; ++r) buf[(32*r + u) * 17 + ww] = xa[hi][r];
    }
    __syncthreads();
    for (int hi = 0; hi < 2; ++hi) {
        int u = q + 16*hi, r1 = u >> 2, j = u & 3, base = 32*r1 + j;
        cplx y[8];
        #pragma unroll
        for (int p = 0; p < 8; ++p) y[p] = buf[(base + 4*p) * 17 + ww];
        dft8<false>(y);
        #pragma unroll
        for (int r2 = 1; r2 < 8; ++r2) y[r2] = cmul(y[r2], tw[8 * j * r2]);
        #pragma unroll
        for (int r2 = 0; r2 < 8; ++r2) buf[(base + 4*r2) * 17 + ww] = y[r2];
    }
    __syncthreads();
    for (int hi2 = 0; hi2 < 4; ++hi2) {
        int m = q + 16*hi2;
        cplx z[4];
        #pragma unroll
        for (int jj = 0; jj < 4; ++jj) z[jj] = buf[(4*m + jj) * 17 + ww];
        dft4<false>(z);
        int kb = (m >> 3) + 8 * (m & 7);
        #pragma unroll
        for (int s2 = 0; s2 < 4; ++s2)
            B[idxB(t, kb + 64*s2, w0 + ww)] = z[s2];
    }
}

// K4: fused w-pass per (kt, 8 kh-lines): read w<128 (contiguous) -> fwd 256 FFT ->
// psf multiply (prefetched to regs) -> inv 256 FFT -> write w<128 in place.
__global__ __launch_bounds__(256, 4) void k4_fftw(
        cplx* __restrict__ B, const float* __restrict__ pr, const float* __restrict__ pim) {
    const int kt = blockIdx.x, kh0 = blockIdx.y * 8;
    const int tid = threadIdx.x, l = tid & 7, q = tid >> 3; // q in [0,32)
    __shared__ cplx buf[256 * 9];
    __shared__ cplx tw[256];
    { float s, c; sincosf(-(2.0f*PI_F/256.0f)*(float)tid, &s, &c); tw[tid] = make_float2(c, s); }
    const size_t lineB = idxB(kt, kh0 + l, 0);
    const size_t lineP = ((size_t)kt * 256 + kh0 + l) * 256;
    // data loads: stage-A octet {q+32p}, p<4 real, p>=4 pad
    cplx x[8];
    #pragma unroll
    for (int p = 0; p < 8; ++p)
        x[p] = (p < 4) ? B[lineB + q + 32*p] : make_float2(0.f, 0.f);
    // psf prefetch (8 freqs/thread: k = kb2[hi] + 64*s2, s2<4)
    int kb2[2];
    kb2[0] = (q >> 3) + 8 * (q & 7);
    kb2[1] = kb2[0] + 4;
    float prf[2][4], pif[2][4];
    #pragma unroll
    for (int hi = 0; hi < 2; ++hi)
        #pragma unroll
        for (int s2 = 0; s2 < 4; ++s2) {
            prf[hi][s2] = pr[lineP + kb2[hi] + 64*s2];
            pif[hi][s2] = pim[lineP + kb2[hi] + 64*s2];
        }
    dft8<false>(x);
    __syncthreads();   // tw ready
    #pragma unroll
    for (int r = 1; r < 8; ++r) x[r] = cmul(x[r], tw[q * r]);
    #pragma unroll
    for (int r = 0; r < 8; ++r) buf[(32*r + q) * 9 + l] = x[r];
    __syncthreads();
    {   // stage B
        int r1 = q >> 2, j = q & 3, base = 32*r1 + j;
        cplx y[8];
        #pragma unroll
        for (int p = 0; p < 8; ++p) y[p] = buf[(base + 4*p) * 9 + l];
        dft8<false>(y);
        #pragma unroll
        for (int r2 = 1; r2 < 8; ++r2) y[r2] = cmul(y[r2], tw[8 * j * r2]);
        #pragma unroll
        for (int r2 = 0; r2 < 8; ++r2) buf[(base + 4*r2) * 9 + l] = y[r2];
    }
    __syncthreads();
    const float S = 1.0f / (512.0f * 256.0f * 256.0f);
    for (int hi = 0; hi < 2; ++hi) {   // stage C + filter + inverse C, in regs
        int m = q + 32*hi;
        cplx z[4];
        #pragma unroll
        for (int jj = 0; jj < 4; ++jj) z[jj] = buf[(4*m + jj) * 9 + l];
        dft4<false>(z);
        #pragma unroll
        for (int s2 = 0; s2 < 4; ++s2)
            z[s2] = cmul(z[s2], make_float2(prf[hi][s2] * S, pif[hi][s2] * S));
        dft4<true>(z);
        #pragma unroll
        for (int jj = 0; jj < 4; ++jj) buf[(4*m + jj) * 9 + l] = z[jj];
    }
    __syncthreads();
    {   // inverse stage B
        int r1 = q >> 2, j = q & 3, base = 32*r1 + j;
        cplx y[8];
        #pragma unroll
        for (int r2 = 0; r2 < 8; ++r2) y[r2] = buf[(base + 4*r2) * 9 + l];
        #pragma unroll
        for (int r2 = 1; r2 < 8; ++r2) y[r2] = cmulc(y[r2], tw[8 * j * r2]);
        dft8<true>(y);
        #pragma unroll
        for (int p = 0; p < 8; ++p) buf[(base + 4*p) * 9 + l] = y[p];
    }
    __syncthreads();
    {   // inverse stage A, write w<128
        cplx xo[8];
        #pragma unroll
        for (int r = 0; r < 8; ++r) xo[r] = buf[(32*r + q) * 9 + l];
        #pragma unroll
        for (int r = 1; r < 8; ++r) xo[r] = cmulc(xo[r], tw[q * r]);
        dft8<true>(xo);
        #pragma unroll
        for (int p = 0; p < 4; ++p) B[lineB + q + 32*p] = xo[p];
    }
}

// K5: inverse 256-FFT along h; reads all h (freq order), writes h<128 in place.
__global__ __launch_bounds__(256, 4) void k5_iffth(cplx* __restrict__ B) {
    const int t = blockIdx.x, w0 = blockIdx.y * 16;
    const int tid = threadIdx.x, ww = tid & 15, q = tid >> 4; // q in [0,16)
    __shared__ cplx buf[256 * 17];
    __shared__ cplx tw[256];
    { float s, c; sincosf(-(2.0f*PI_F/256.0f)*(float)tid, &s, &c); tw[tid] = make_float2(c, s); }
    cplx za[4][4];
    for (int hi2 = 0; hi2 < 4; ++hi2) {
        int m = q + 16*hi2, kb = (m >> 3) + 8 * (m & 7);
        #pragma unroll
        for (int s2 = 0; s2 < 4; ++s2) za[hi2][s2] = B[idxB(t, kb + 64*s2, w0 + ww)];
    }
    for (int hi2 = 0; hi2 < 4; ++hi2) {
        int m = q + 16*hi2;
        dft4<true>(za[hi2]);
        #pragma unroll
        for (int jj = 0; jj < 4; ++jj) buf[(4*m + jj) * 17 + ww] = za[hi2][jj];
    }
    __syncthreads();   // covers tw + buf
    for (int hi = 0; hi < 2; ++hi) {
        int u = q + 16*hi, r1 = u >> 2, j = u & 3, base = 32*r1 + j;
        cplx y[8];
        #pragma unroll
        for (int r2 = 0; r2 < 8; ++r2) y[r2] = buf[(base + 4*r2) * 17 + ww];
        #pragma unroll
        for (int r2 = 1; r2 < 8; ++r2) y[r2] = cmulc(y[r2], tw[8 * j * r2]);
        dft8<true>(y);
        #pragma unroll
        for (int p = 0; p < 8; ++p) buf[(base + 4*p) * 17 + ww] = y[p];
    }
    __syncthreads();
    for (int hi = 0; hi < 2; ++hi) {
        int u = q + 16*hi;
        cplx xo[8];
        #pragma unroll
        for (int r = 0; r < 8; ++r) xo[r] = buf[(32*r + u) * 17 + ww];
        #pragma unroll
        for (int r = 1; r < 8; ++r) xo[r] = cmulc(xo[r], tw[u * r]);
        dft8<true>(xo);
        #pragma unroll
        for (int p = 0; p < 4; ++p) B[idxB(t, u + 32*p, w0 + ww)] = xo[p];
    }
}

// K6: inverse 512-FFT along t; reads all t at h<128, writes t<256 in place.
__global__ __launch_bounds__(512, 4) void k6_ifftt(cplx* __restrict__ B) {
    const int h = blockIdx.x, w0 = blockIdx.y * 16;
    const int tid = threadIdx.x, ww = tid & 15, q = tid >> 4; // q in [0,32)
    __shared__ cplx buf[512 * 17];
    __shared__ cplx tw[512];
    { float s, c; sincosf(-(2.0f*PI_F/512.0f)*(float)tid, &s, &c); tw[tid] = make_float2(c, s); }
    cplx za[2][8];
    for (int hi = 0; hi < 2; ++hi) {
        int m = q + 32*hi, kb = (m >> 3) + 8 * (m & 7);
        #pragma unroll
        for (int s2 = 0; s2 < 8; ++s2) za[hi][s2] = B[idxB(kb + 64*s2, h, w0 + ww)];
    }
    for (int hi = 0; hi < 2; ++hi) {
        int m = q + 32*hi;
        dft8<true>(za[hi]);
        #pragma unroll
        for (int jj = 0; jj < 8; ++jj) buf[(8*m + jj) * 17 + ww] = za[hi][jj];
    }
    __syncthreads();   // covers tw + buf
    for (int hi = 0; hi < 2; ++hi) {
        int u = q + 32*hi, r1 = u >> 3, j = u & 7, base = 64*r1 + j;
        cplx y[8];
        #pragma unroll
        for (int r2 = 0; r2 < 8; ++r2) y[r2] = buf[(base + 8*r2) * 17 + ww];
        #pragma unroll
        for (int r2 = 1; r2 < 8; ++r2) y[r2] = cmulc(y[r2], tw[8 * j * r2]);
        dft8<true>(y);
        #pragma unroll
        for (int p = 0; p < 8; ++p) buf[(base + 8*p) * 17 + ww] = y[p];
    }
    __syncthreads();
    for (int hi = 0; hi < 2; ++hi) {
        int u = q + 32*hi;
        cplx xo[8];
        #pragma unroll
        for (int r = 0; r < 8; ++r) xo[r] = buf[(64*r + u) * 17 + ww];
        #pragma unroll
        for (int r = 1; r < 8; ++r) xo[r] = cmulc(xo[r], tw[u * r]);
        dft8<true>(xo);
        #pragma unroll
        for (int p = 0; p < 4; ++p) B[idxB(u + 64*p, h, w0 + ww)] = xo[p];
    }
}

// K7: out[d,m,h,w] = sum_t mtxi[m,t] * vol[t,h,w]; Re->d0, Im->d1.
__global__ __launch_bounds__(128) void k7_out(
        const cplx* __restrict__ B, const float* __restrict__ mtxi,
        float* __restrict__ out) {
    int m = blockIdx.x, h = blockIdx.y, w = threadIdx.x;
    __shared__ float coeff[256];
    for (int k = threadIdx.x; k < 256; k += 128)
        coeff[k] = mtxi[m * 256 + k];
    __syncthreads();
    float a0 = 0.f, a1 = 0.f;
    for (int t = 0; t < 256; ++t) {
        float c = coeff[t];
        if (c != 0.0f) {
            cplx v = B[idxB(t, h, w)];
            a0 += c * v.x;
            a1 += c * v.y;
        }
    }
    out[((size_t)m * 128 + h) * 128 + w] = a0;
    out[(((size_t)256 + m) * 128 + h) * 128 + w] = a1;
}

extern "C" void kernel_launch(void* const* d_in, const int* in_sizes, int n_in,
                              void* d_out, int out_size, void* d_ws, size_t ws_size,
                              hipStream_t stream) {
    const float* feat  = (const float*)d_in[0];
    const float* gridz = (const float*)d_in[1];
    const float* mtx   = (const float*)d_in[2];
    const float* mtxi  = (const float*)d_in[3];
    const float* pr    = (const float*)d_in[4];
    const float* pim   = (const float*)d_in[5];
    cplx* B = (cplx*)d_ws; // 512*256*128*8 = 134,217,728 bytes
    float* out = (float*)d_out;

    k1_resample<<<dim3(256, 128), 128, 0, stream>>>(feat, gridz, mtx, B);
    k2_fftt    <<<dim3(128, 8), 512, 0, stream>>>(B);
    k3_ffth    <<<dim3(512, 8), 256, 0, stream>>>(B);
    k4_fftw    <<<dim3(512, 32), 256, 0, stream>>>(B, pr, pim);
    k5_iffth   <<<dim3(512, 8), 256, 0, stream>>>(B);
    k6_ifftt   <<<dim3(128, 8), 512, 0, stream>>>(B);
    k7_out     <<<dim3(256, 128), 128, 0, stream>>>(B, mtxi, out);
}

// Round 5
// 497.363 us; speedup vs baseline: 1.9630x; 1.4190x over previous
//
#include <hip/hip_runtime.h>
#include <math.h>

typedef float2 cplx;
#define PI_F 3.14159265358979323846f
#define C8F 0.70710678118654752440f

__device__ __forceinline__ cplx cadd(cplx a, cplx b){ return make_float2(a.x+b.x, a.y+b.y); }
__device__ __forceinline__ cplx csub(cplx a, cplx b){ return make_float2(a.x-b.x, a.y-b.y); }
__device__ __forceinline__ cplx cmul(cplx a, cplx b){ return make_float2(a.x*b.x - a.y*b.y, a.x*b.y + a.y*b.x); }
__device__ __forceinline__ cplx cmulc(cplx a, cplx b){ return make_float2(a.x*b.x + a.y*b.y, a.y*b.x - a.x*b.y); }
__device__ __forceinline__ cplx cax(float s, cplx v){ return make_float2(s*v.x, s*v.y); }

template<bool INV>
__device__ __forceinline__ void dft8(cplx* v) {
    cplx t0 = cadd(v[0], v[4]), u0 = csub(v[0], v[4]);
    cplx t1 = cadd(v[1], v[5]), u1 = csub(v[1], v[5]);
    cplx t2 = cadd(v[2], v[6]), u2 = csub(v[2], v[6]);
    cplx t3 = cadd(v[3], v[7]), u3 = csub(v[3], v[7]);
    if (!INV) {
        u1 = make_float2(C8F*(u1.x + u1.y), C8F*(u1.y - u1.x));
        u2 = make_float2(u2.y, -u2.x);
        u3 = make_float2(C8F*(u3.y - u3.x), -C8F*(u3.x + u3.y));
    } else {
        u1 = make_float2(C8F*(u1.x - u1.y), C8F*(u1.x + u1.y));
        u2 = make_float2(-u2.y, u2.x);
        u3 = make_float2(-C8F*(u3.x + u3.y), C8F*(u3.x - u3.y));
    }
    cplx b0 = cadd(t0,t2), b1 = cadd(t1,t3), b2 = csub(t0,t2), b3 = csub(t1,t3);
    b3 = INV ? make_float2(-b3.y, b3.x) : make_float2(b3.y, -b3.x);
    v[0] = cadd(b0,b1); v[4] = csub(b0,b1); v[2] = cadd(b2,b3); v[6] = csub(b2,b3);
    cplx c0 = cadd(u0,u2), c1 = cadd(u1,u3), c2 = csub(u0,u2), c3 = csub(u1,u3);
    c3 = INV ? make_float2(-c3.y, c3.x) : make_float2(c3.y, -c3.x);
    v[1] = cadd(c0,c1); v[5] = csub(c0,c1); v[3] = cadd(c2,c3); v[7] = csub(c2,c3);
}

template<bool INV>
__device__ __forceinline__ void dft4(cplx* v) {
    cplx b0 = cadd(v[0], v[2]), b2 = csub(v[0], v[2]);
    cplx b1 = cadd(v[1], v[3]), b3 = csub(v[1], v[3]);
    b3 = INV ? make_float2(-b3.y, b3.x) : make_float2(b3.y, -b3.x);
    v[0] = cadd(b0,b1); v[2] = csub(b0,b1); v[1] = cadd(b2,b3); v[3] = csub(b2,b3);
}

// 16-point DFT, natural in/out. X[c+4d] = sum_a W16^{ac} W4^{ad} (sum_b x[a+4b] W4^{bc})
template<bool INV>
__device__ __forceinline__ void dft16(cplx* v) {
    #pragma unroll
    for (int a = 0; a < 4; ++a) {
        cplx t[4] = { v[a], v[a+4], v[a+8], v[a+12] };
        dft4<INV>(t);
        v[a] = t[0]; v[a+4] = t[1]; v[a+8] = t[2]; v[a+12] = t[3];
    }
    const float C1 = 0.92387953251128674f, S1 = 0.38268343236508978f, R2 = 0.70710678118654752f;
    #define TWX(idx, CR, CI) v[idx] = cmul(v[idx], make_float2(CR, INV ? -(CI) : (CI)))
    TWX(1+4*1,  C1, -S1);   // W16^1
    TWX(1+4*2,  R2, -R2);   // W16^2
    TWX(1+4*3,  S1, -C1);   // W16^3
    TWX(2+4*1,  R2, -R2);   // W16^2
    TWX(2+4*2, 0.f, -1.f);  // W16^4
    TWX(2+4*3, -R2, -R2);   // W16^6
    TWX(3+4*1,  S1, -C1);   // W16^3
    TWX(3+4*2, -R2, -R2);   // W16^6
    TWX(3+4*3, -C1,  S1);   // W16^9
    #undef TWX
    cplx o[16];
    #pragma unroll
    for (int c = 0; c < 4; ++c) {
        cplx t[4] = { v[4*c+0], v[4*c+1], v[4*c+2], v[4*c+3] };
        dft4<INV>(t);
        o[c] = t[0]; o[c+4] = t[1]; o[c+8] = t[2]; o[c+12] = t[3];
    }
    #pragma unroll
    for (int i = 0; i < 16; ++i) v[i] = o[i];
}

// swizzled twiddle-table index (breaks bank collisions for strided products)
__device__ __forceinline__ int twp(int i){ return i + (i >> 4); }

// B: [512 t][256 h][128 w] cplx = 128 MiB (all of d_ws).
__host__ __device__ __forceinline__ size_t idxB(int t, int h, int w) {
    return ((size_t)t * 256 + h) * 128 + w;
}

// K0a: compact row m of (mtx * gridz^4) into <=16 (val,col) pairs (banded).
__global__ __launch_bounds__(256) void k0_mtx(
        const float* __restrict__ mtx, const float* __restrict__ gridz,
        float* __restrict__ tv, int* __restrict__ tc) {
    int m = blockIdx.x, t = threadIdx.x;
    __shared__ float rv[256];
    float g = gridz[t]; float g2 = g * g;
    rv[t] = mtx[m * 256 + t] * (g2 * g2);
    __syncthreads();
    if (t == 0) {
        int cnt = 0;
        for (int k = 0; k < 256 && cnt < 16; ++k)
            if (rv[k] != 0.f) { tv[m*16 + cnt] = rv[k]; tc[m*16 + cnt] = k; ++cnt; }
        for (; cnt < 16; ++cnt) { tv[m*16 + cnt] = 0.f; tc[m*16 + cnt] = 0; }
    }
}

// K0b: compact row m of mtxi into <=8 (val,col) pairs.
__global__ __launch_bounds__(256) void k0_mtxi(
        const float* __restrict__ mtxi, float* __restrict__ tv, int* __restrict__ tc) {
    int m = blockIdx.x, t = threadIdx.x;
    __shared__ float rv[256];
    rv[t] = mtxi[m * 256 + t];
    __syncthreads();
    if (t == 0) {
        int cnt = 0;
        for (int k = 0; k < 256 && cnt < 8; ++k)
            if (rv[k] != 0.f) { tv[m*8 + cnt] = rv[k]; tc[m*8 + cnt] = k; ++cnt; }
        for (; cnt < 8; ++cnt) { tv[m*8 + cnt] = 0.f; tc[m*8 + cnt] = 0; }
    }
}

// K2': fused resample + forward 512-FFT along t. Reads feat, writes B[all t, h<128].
__global__ __launch_bounds__(512, 2) void k2_fftt(
        const float* __restrict__ feat, const float* __restrict__ tv,
        const int* __restrict__ tc, cplx* __restrict__ B) {
    const int h = blockIdx.x, w0 = blockIdx.y * 16;
    const int tid = threadIdx.x, ww = tid & 15, q = tid >> 4; // q in [0,32)
    __shared__ cplx buf[512 * 17];
    __shared__ cplx tw[512];
    { float s, c; sincosf(-(2.0f*PI_F/512.0f)*(float)tid, &s, &c); tw[tid] = make_float2(c, s); }
    // stage feat (both channels packed re+i*im) into LDS: f2[t*16+ww], t<256
    cplx* f2 = buf;
    for (int idx = tid; idx < 4096; idx += 512) {
        int t = idx >> 4, w = idx & 15;
        size_t o = ((size_t)t * 128 + h) * 128 + w0 + w;
        f2[idx] = make_float2(feat[o], feat[o + 4194304]);
    }
    __syncthreads();
    // sparse matvec: A[m] = sum_j val[m,j] * f2[col[m,j]]  (table broadcast across ww)
    cplx xa[2][8];
    for (int hi = 0; hi < 2; ++hi) {
        int u = q + 32*hi;
        #pragma unroll
        for (int p = 0; p < 8; ++p) {
            if (p < 4) {
                int m = u + 64*p;
                cplx acc = make_float2(0.f, 0.f);
                const float4* v4 = (const float4*)(tv + m*16);
                const int4*  c4 = (const int4*)(tc + m*16);
                #pragma unroll
                for (int jj = 0; jj < 4; ++jj) {
                    float4 vv = v4[jj]; int4 cc = c4[jj];
                    acc = cadd(acc, cax(vv.x, f2[cc.x*16 + ww]));
                    acc = cadd(acc, cax(vv.y, f2[cc.y*16 + ww]));
                    acc = cadd(acc, cax(vv.z, f2[cc.z*16 + ww]));
                    acc = cadd(acc, cax(vv.w, f2[cc.w*16 + ww]));
                }
                xa[hi][p] = acc;
            } else xa[hi][p] = make_float2(0.f, 0.f);
        }
    }
    dft8<false>(xa[0]); dft8<false>(xa[1]);
    __syncthreads();   // all f2 reads done before stage-A overwrites
    for (int hi = 0; hi < 2; ++hi) {
        int u = q + 32*hi;
        #pragma unroll
        for (int r = 1; r < 8; ++r) xa[hi][r] = cmul(xa[hi][r], tw[u * r]);
        #pragma unroll
        for (int r = 0; r < 8; ++r) buf[(64*r + u) * 17 + ww] = xa[hi][r];
    }
    __syncthreads();
    for (int hi = 0; hi < 2; ++hi) {
        int u = q + 32*hi, r1 = u >> 3, j = u & 7, base = 64*r1 + j;
        cplx y[8];
        #pragma unroll
        for (int p = 0; p < 8; ++p) y[p] = buf[(base + 8*p) * 17 + ww];
        dft8<false>(y);
        #pragma unroll
        for (int r2 = 1; r2 < 8; ++r2) y[r2] = cmul(y[r2], tw[8 * j * r2]);
        #pragma unroll
        for (int r2 = 0; r2 < 8; ++r2) buf[(base + 8*r2) * 17 + ww] = y[r2];
    }
    __syncthreads();
    for (int hi = 0; hi < 2; ++hi) {
        int m = q + 32*hi;
        cplx z[8];
        #pragma unroll
        for (int r = 0; r < 8; ++r) z[r] = buf[(8*m + r) * 17 + ww];
        dft8<false>(z);
        int kb = (m >> 3) + 8 * (m & 7);
        #pragma unroll
        for (int s2 = 0; s2 < 8; ++s2)
            B[idxB(kb + 64*s2, h, w0 + ww)] = z[s2];
    }
}

// K3: forward 256-FFT along h, radix-16^2, 1 LDS exchange. Reads h<128, writes all h.
__global__ __launch_bounds__(256) void k3_ffth(cplx* __restrict__ B) {
    const int t = blockIdx.x, w0 = blockIdx.y * 16;
    const int tid = threadIdx.x, ww = tid & 15, q = tid >> 4; // q in [0,16)
    __shared__ cplx buf[256 * 16];
    __shared__ cplx tw[272];
    { float s, c; sincosf(-(2.0f*PI_F/256.0f)*(float)tid, &s, &c); tw[twp(tid)] = make_float2(c, s); }
    cplx x[16];
    #pragma unroll
    for (int n2 = 0; n2 < 8; ++n2) x[n2] = B[idxB(t, q + 16*n2, w0 + ww)];
    #pragma unroll
    for (int n2 = 8; n2 < 16; ++n2) x[n2] = make_float2(0.f, 0.f);
    dft16<false>(x);                 // over n2 -> k2
    __syncthreads();                 // tw ready
    #pragma unroll
    for (int k2 = 1; k2 < 16; ++k2) x[k2] = cmul(x[k2], tw[twp(q * k2)]);
    #pragma unroll
    for (int k2 = 0; k2 < 16; ++k2) buf[(q + 16*k2) * 16 + ww] = x[k2];
    __syncthreads();
    cplx z[16];
    #pragma unroll
    for (int n1 = 0; n1 < 16; ++n1) z[n1] = buf[(n1 + 16*q) * 16 + ww];
    dft16<false>(z);                 // over n1 -> k1; h = q + 16*k1
    #pragma unroll
    for (int k1 = 0; k1 < 16; ++k1) B[idxB(t, q + 16*k1, w0 + ww)] = z[k1];
}

// K4: fused w-pass, radix-16^2: read w<128 -> fwd 256 FFT -> psf multiply (regs) ->
// inv 256 FFT -> write w<128. 3 syncs, XOR-swizzled LDS.
__global__ __launch_bounds__(256) void k4_fftw(
        cplx* __restrict__ B, const float* __restrict__ pr, const float* __restrict__ pim) {
    const int kt = blockIdx.x, kh0 = blockIdx.y * 16;
    const int tid = threadIdx.x, q = tid & 15, l = tid >> 4; // q fast for w-coalescing
    __shared__ cplx buf[16 * 256];
    __shared__ cplx tw[272];
    { float s, c; sincosf(-(2.0f*PI_F/256.0f)*(float)tid, &s, &c); tw[twp(tid)] = make_float2(c, s); }
    const size_t lineB = idxB(kt, kh0 + l, 0);
    const size_t lineP = ((size_t)kt * 256 + kh0 + l) * 256;
    cplx x[16];
    #pragma unroll
    for (int n2 = 0; n2 < 8; ++n2) x[n2] = B[lineB + q + 16*n2];
    #pragma unroll
    for (int n2 = 8; n2 < 16; ++n2) x[n2] = make_float2(0.f, 0.f);
    float prv[16], piv[16];
    #pragma unroll
    for (int k1 = 0; k1 < 16; ++k1) {
        prv[k1] = pr[lineP + q + 16*k1];
        piv[k1] = pim[lineP + q + 16*k1];
    }
    dft16<false>(x);
    __syncthreads();                 // tw ready
    #pragma unroll
    for (int k2 = 1; k2 < 16; ++k2) x[k2] = cmul(x[k2], tw[twp(q * k2)]);
    #pragma unroll
    for (int k2 = 0; k2 < 16; ++k2) buf[l*256 + (q ^ k2) + 16*k2] = x[k2];
    __syncthreads();
    cplx z[16];
    #pragma unroll
    for (int n1 = 0; n1 < 16; ++n1) z[n1] = buf[l*256 + (n1 ^ q) + 16*q];
    dft16<false>(z);                 // z[k1] = X[q + 16*k1]
    const float S = 1.0f / (512.0f * 256.0f * 256.0f);
    #pragma unroll
    for (int k1 = 0; k1 < 16; ++k1)
        z[k1] = cmul(z[k1], make_float2(prv[k1]*S, piv[k1]*S));
    dft16<true>(z);                  // inverse over k1 -> n1
    #pragma unroll
    for (int n1 = 1; n1 < 16; ++n1) z[n1] = cmulc(z[n1], tw[twp(n1 * q)]);
    #pragma unroll
    for (int n1 = 0; n1 < 16; ++n1) buf[l*256 + (n1 ^ q) + 16*q] = z[n1]; // own column
    __syncthreads();
    cplx y[16];
    #pragma unroll
    for (int k2 = 0; k2 < 16; ++k2) y[k2] = buf[l*256 + (q ^ k2) + 16*k2];
    dft16<true>(y);                  // over k2 -> n2; w = q + 16*n2
    #pragma unroll
    for (int n2 = 0; n2 < 8; ++n2) B[lineB + q + 16*n2] = y[n2];
}

// K5: inverse 256-FFT along h, radix-16^2. Reads all h (natural freq), writes h<128.
__global__ __launch_bounds__(256) void k5_iffth(cplx* __restrict__ B) {
    const int t = blockIdx.x, w0 = blockIdx.y * 16;
    const int tid = threadIdx.x, ww = tid & 15, q = tid >> 4;
    __shared__ cplx buf[256 * 16];
    __shared__ cplx tw[272];
    { float s, c; sincosf(-(2.0f*PI_F/256.0f)*(float)tid, &s, &c); tw[twp(tid)] = make_float2(c, s); }
    cplx x[16];
    #pragma unroll
    for (int k1 = 0; k1 < 16; ++k1) x[k1] = B[idxB(t, q + 16*k1, w0 + ww)]; // q = k2
    dft16<true>(x);                  // over k1 -> n1
    __syncthreads();
    #pragma unroll
    for (int n1 = 1; n1 < 16; ++n1) x[n1] = cmulc(x[n1], tw[twp(n1 * q)]);
    #pragma unroll
    for (int n1 = 0; n1 < 16; ++n1) buf[(n1 + 16*q) * 16 + ww] = x[n1];
    __syncthreads();
    cplx z[16];
    #pragma unroll
    for (int k2 = 0; k2 < 16; ++k2) z[k2] = buf[(q + 16*k2) * 16 + ww]; // q = n1
    dft16<true>(z);                  // over k2 -> n2; h = q + 16*n2
    #pragma unroll
    for (int n2 = 0; n2 < 8; ++n2) B[idxB(t, q + 16*n2, w0 + ww)] = z[n2];
}

// K6': inverse 512-FFT along t fused with mtxi output matvec. Writes d_out only.
__global__ __launch_bounds__(512, 2) void k6_ifftt(
        cplx* __restrict__ B, const float* __restrict__ tv, const int* __restrict__ tc,
        float* __restrict__ out) {
    const int h = blockIdx.x, w0 = blockIdx.y * 16;
    const int tid = threadIdx.x, ww = tid & 15, q = tid >> 4; // q in [0,32)
    __shared__ cplx buf[512 * 17];
    __shared__ cplx tw[512];
    { float s, c; sincosf(-(2.0f*PI_F/512.0f)*(float)tid, &s, &c); tw[tid] = make_float2(c, s); }
    cplx za[2][8];
    for (int hi = 0; hi < 2; ++hi) {
        int m = q + 32*hi, kb = (m >> 3) + 8 * (m & 7);
        #pragma unroll
        for (int s2 = 0; s2 < 8; ++s2) za[hi][s2] = B[idxB(kb + 64*s2, h, w0 + ww)];
    }
    for (int hi = 0; hi < 2; ++hi) {
        int m = q + 32*hi;
        dft8<true>(za[hi]);
        #pragma unroll
        for (int jj = 0; jj < 8; ++jj) buf[(8*m + jj) * 17 + ww] = za[hi][jj];
    }
    __syncthreads();   // covers tw + buf
    for (int hi = 0; hi < 2; ++hi) {
        int u = q + 32*hi, r1 = u >> 3, j = u & 7, base = 64*r1 + j;
        cplx y[8];
        #pragma unroll
        for (int r2 = 0; r2 < 8; ++r2) y[r2] = buf[(base + 8*r2) * 17 + ww];
        #pragma unroll
        for (int r2 = 1; r2 < 8; ++r2) y[r2] = cmulc(y[r2], tw[8 * j * r2]);
        dft8<true>(y);
        #pragma unroll
        for (int p = 0; p < 8; ++p) buf[(base + 8*p) * 17 + ww] = y[p];
    }
    __syncthreads();
    cplx vol[2][4];
    for (int hi = 0; hi < 2; ++hi) {
        int u = q + 32*hi;
        cplx xo[8];
        #pragma unroll
        for (int r = 0; r < 8; ++r) xo[r] = buf[(64*r + u) * 17 + ww];
        #pragma unroll
        for (int r = 1; r < 8; ++r) xo[r] = cmulc(xo[r], tw[u * r]);
        dft8<true>(xo);
        #pragma unroll
        for (int p = 0; p < 4; ++p) vol[hi][p] = xo[p];  // t = u + 64p < 256
    }
    __syncthreads();   // all buf reads done before vol overwrite
    for (int hi = 0; hi < 2; ++hi) {
        int u = q + 32*hi;
        #pragma unroll
        for (int p = 0; p < 4; ++p) buf[(u + 64*p) * 16 + ww] = vol[hi][p];
    }
    __syncthreads();
    // out[m] = sum_j val[m,j] * vol[col[m,j]]  (table broadcast across ww)
    for (int hi = 0; hi < 2; ++hi) {
        int u = q + 32*hi;
        #pragma unroll
        for (int p = 0; p < 4; ++p) {
            int m = u + 64*p;
            cplx acc = make_float2(0.f, 0.f);
            const float4* v4 = (const float4*)(tv + m*8);
            const int4*  c4 = (const int4*)(tc + m*8);
            #pragma unroll
            for (int jj = 0; jj < 2; ++jj) {
                float4 vv = v4[jj]; int4 cc = c4[jj];
                acc = cadd(acc, cax(vv.x, buf[cc.x*16 + ww]));
                acc = cadd(acc, cax(vv.y, buf[cc.y*16 + ww]));
                acc = cadd(acc, cax(vv.z, buf[cc.z*16 + ww]));
                acc = cadd(acc, cax(vv.w, buf[cc.w*16 + ww]));
            }
            out[((size_t)m * 128 + h) * 128 + w0 + ww] = acc.x;
            out[(((size_t)256 + m) * 128 + h) * 128 + w0 + ww] = acc.y;
        }
    }
}

extern "C" void kernel_launch(void* const* d_in, const int* in_sizes, int n_in,
                              void* d_out, int out_size, void* d_ws, size_t ws_size,
                              hipStream_t stream) {
    const float* feat  = (const float*)d_in[0];
    const float* gridz = (const float*)d_in[1];
    const float* mtx   = (const float*)d_in[2];
    const float* mtxi  = (const float*)d_in[3];
    const float* pr    = (const float*)d_in[4];
    const float* pim   = (const float*)d_in[5];
    cplx* B = (cplx*)d_ws; // 512*256*128*8 = 128 MiB
    float* out = (float*)d_out;

    // mtx table in dead region [t=257, h>=128] (dead until k3 writes; consumed by k2')
    float* T1v = (float*)(B + idxB(257, 128, 0));
    int*   T1c = (int*)(T1v + 4096);
    // mtxi table in dead region [t=0, h>=128] (built after k5; consumed by k6')
    float* T2v = (float*)(B + idxB(0, 128, 0));
    int*   T2c = (int*)(T2v + 2048);

    k0_mtx <<<256, 256, 0, stream>>>(mtx, gridz, T1v, T1c);
    k2_fftt<<<dim3(128, 8), 512, 0, stream>>>(feat, T1v, T1c, B);
    k3_ffth<<<dim3(512, 8), 256, 0, stream>>>(B);
    k4_fftw<<<dim3(512, 16), 256, 0, stream>>>(B, pr, pim);
    k5_iffth<<<dim3(512, 8), 256, 0, stream>>>(B);
    k0_mtxi<<<256, 256, 0, stream>>>(mtxi, T2v, T2c);
    k6_ifftt<<<dim3(128, 8), 512, 0, stream>>>(B, T2v, T2c, out);
}